// Round 4
// baseline (574.939 us; speedup 1.0000x reference)
//
#include <hip/hip_runtime.h>
#include <math.h>

#define D_IN 64
#define D_H 40
#define D_OUT 24
#define S_BITS 8
#define S_NODES 256      // nodes per bucket
#define CH 8192          // edges per passA/passB block
#define BMAX 512         // max buckets (n <= 131072)

typedef unsigned int u32;
typedef unsigned short u16;

// ---------------- CSR build: atomic-free LDS multisplit ----------------
// passA: per-block histogram of dst buckets (bucket = dst >> 8).
// int4-vectorized edge reads: 4 edges/thread/iter, 1KB/wave-instr.
__global__ void passA(const int* __restrict__ dst, int* __restrict__ G,
                      int E, int B) {
    __shared__ int hist[BMAX];
    int tx = threadIdx.x;
    for (int i = tx; i < B; i += 256) hist[i] = 0;
    __syncthreads();
    int e0 = blockIdx.x * CH;
    int e1 = min(e0 + CH, E);
    for (int e = e0 + tx * 4; e < e1; e += 1024) {
        if (e + 4 <= e1) {
            int4 d4 = *(const int4*)(dst + e);
            atomicAdd(&hist[d4.x >> S_BITS], 1);
            atomicAdd(&hist[d4.y >> S_BITS], 1);
            atomicAdd(&hist[d4.z >> S_BITS], 1);
            atomicAdd(&hist[d4.w >> S_BITS], 1);
        } else {
            for (int q = e; q < e1; ++q)
                atomicAdd(&hist[dst[q] >> S_BITS], 1);
        }
    }
    __syncthreads();
    for (int i = tx; i < B; i += 256) G[(size_t)blockIdx.x * B + i] = hist[i];
}

// colscan: for bucket b, exclusive-scan G[i][b] over blocks i; total -> bktTotal.
__global__ void colscan(int* __restrict__ G, int* __restrict__ bktTotal,
                        int NB1, int B) {
    int b = blockIdx.x;
    int lane = threadIdx.x;      // 64 threads
    int carry = 0;
    for (int base = 0; base < NB1; base += 64) {
        int i = base + lane;
        int orig = (i < NB1) ? G[(size_t)i * B + b] : 0;
        int v = orig;
        #pragma unroll
        for (int d = 1; d < 64; d <<= 1) {
            int t = __shfl_up(v, d);
            if (lane >= d) v += t;
        }
        if (i < NB1) G[(size_t)i * B + b] = carry + v - orig;   // exclusive
        carry += __shfl(v, 63);
    }
    if (lane == 0) bktTotal[b] = carry;
}

// bucketscan: exclusive scan of bucket totals -> bktStart[0..B]; off[n] = E.
__global__ void bucketscan(const int* __restrict__ bktTotal,
                           int* __restrict__ bktStart, int* __restrict__ off,
                           int B, int E, int n) {
    int lane = threadIdx.x;
    int carry = 0;
    for (int base = 0; base < B; base += 64) {
        int i = base + lane;
        int orig = (i < B) ? bktTotal[i] : 0;
        int v = orig;
        #pragma unroll
        for (int d = 1; d < 64; d <<= 1) {
            int t = __shfl_up(v, d);
            if (lane >= d) v += t;
        }
        if (i < B) bktStart[i] = carry + v - orig;
        carry += __shfl(v, 63);
    }
    if (lane == 0) { bktStart[B] = carry; off[n] = E; }
}

// passB: scatter edges into bucket-major order, packed (dstl<<24 | src).
// int4-vectorized src/dst reads; scatter stores unchanged (bucket content is
// order-insensitive: per-node ranks were already atomic-race-ordered).
__global__ void passB(const int* __restrict__ src, const int* __restrict__ dst,
                      const int* __restrict__ G, const int* __restrict__ bktStart,
                      u32* __restrict__ bucketed, int E, int B) {
    __shared__ int baseS[BMAX];
    __shared__ int cnt[BMAX];
    int tx = threadIdx.x;
    for (int i = tx; i < B; i += 256) {
        baseS[i] = bktStart[i] + G[(size_t)blockIdx.x * B + i];
        cnt[i] = 0;
    }
    __syncthreads();
    int e0 = blockIdx.x * CH;
    int e1 = min(e0 + CH, E);
    for (int e = e0 + tx * 4; e < e1; e += 1024) {
        if (e + 4 <= e1) {
            int4 d4 = *(const int4*)(dst + e);
            int4 s4 = *(const int4*)(src + e);
            int b0 = d4.x >> S_BITS, b1 = d4.y >> S_BITS;
            int b2 = d4.z >> S_BITS, b3 = d4.w >> S_BITS;
            int r0 = atomicAdd(&cnt[b0], 1);
            int r1 = atomicAdd(&cnt[b1], 1);
            int r2 = atomicAdd(&cnt[b2], 1);
            int r3 = atomicAdd(&cnt[b3], 1);
            bucketed[baseS[b0] + r0] = ((u32)(d4.x & (S_NODES - 1)) << 24) | (u32)s4.x;
            bucketed[baseS[b1] + r1] = ((u32)(d4.y & (S_NODES - 1)) << 24) | (u32)s4.y;
            bucketed[baseS[b2] + r2] = ((u32)(d4.z & (S_NODES - 1)) << 24) | (u32)s4.z;
            bucketed[baseS[b3] + r3] = ((u32)(d4.w & (S_NODES - 1)) << 24) | (u32)s4.w;
        } else {
            for (int q = e; q < e1; ++q) {
                int d = dst[q];
                int b = d >> S_BITS;
                int r = atomicAdd(&cnt[b], 1);
                bucketed[baseS[b] + r] = ((u32)(d & (S_NODES - 1)) << 24) | (u32)src[q];
            }
        }
    }
}

// bucket_csr: one block per bucket. Count 256 local nodes, LDS scan -> off,
// then rank+place into final CSR. No global scan, no global atomics.
__global__ void bucket_csr(const u32* __restrict__ bucketed,
                           const int* __restrict__ bktStart,
                           int* __restrict__ off, int* __restrict__ csr,
                           int n) {
    __shared__ int degl[S_NODES];
    __shared__ int offl[S_NODES + 1];
    __shared__ int cntl[S_NODES];
    int b  = blockIdx.x;
    int tx = threadIdx.x;        // 256
    int bs = bktStart[b], be = bktStart[b + 1];
    degl[tx] = 0;
    cntl[tx] = 0;
    __syncthreads();
    for (int e = bs + tx; e < be; e += 256)
        atomicAdd(&degl[bucketed[e] >> 24], 1);      // LDS atomic
    __syncthreads();
    int v = degl[tx];
    offl[tx] = v;
    __syncthreads();
    for (int d = 1; d < 256; d <<= 1) {              // Hillis-Steele inclusive
        int t = (tx >= d) ? offl[tx - d] : 0;
        __syncthreads();
        offl[tx] += t;
        __syncthreads();
    }
    int excl = offl[tx] - v;
    __syncthreads();
    offl[tx] = excl;
    if (tx == 255) offl[256] = excl + v;
    __syncthreads();
    int node = b * S_NODES + tx;
    if (node <= n) off[node] = bs + offl[tx];
    for (int e = bs + tx; e < be; e += 256) {
        u32 w = bucketed[e];
        int dl = w >> 24;
        int r = atomicAdd(&cntl[dl], 1);             // LDS atomic
        csr[bs + offl[dl] + r] = (int)(w & 0xFFFFFFu);
    }
}

// ---------------- bf16 helpers ----------------
__device__ inline u16 f32_to_bf16_rne(float f) {
    u32 u = __float_as_uint(f);
    u += 0x7fffu + ((u >> 16) & 1u);
    return (u16)(u >> 16);
}

__device__ inline void accum8(float* a, uint4 w) {
    a[0] += __uint_as_float(w.x << 16);
    a[1] += __uint_as_float(w.x & 0xffff0000u);
    a[2] += __uint_as_float(w.y << 16);
    a[3] += __uint_as_float(w.y & 0xffff0000u);
    a[4] += __uint_as_float(w.z << 16);
    a[5] += __uint_as_float(w.z & 0xffff0000u);
    a[6] += __uint_as_float(w.w << 16);
    a[7] += __uint_as_float(w.w & 0xffff0000u);
}

__device__ inline float dot16(const float4* __restrict__ w, const float4* v) {
    float acc = 0.0f;
    #pragma unroll
    for (int k = 0; k < 16; ++k) {
        float4 a = w[k], b = v[k];
        acc += a.x * b.x + a.y * b.y + a.z * b.z + a.w * b.w;
    }
    return acc;
}

__device__ inline float dot10(const float4* __restrict__ w, const float4* v) {
    float acc = 0.0f;
    #pragma unroll
    for (int k = 0; k < 10; ++k) {
        float4 a = w[k], b = v[k];
        acc += a.x * b.x + a.y * b.y + a.z * b.z + a.w * b.w;
    }
    return acc;
}

// ---------------- pre1: xl = bf16(x@W1l^T), xr = x@W1r^T + b1 ----------------
// Rewritten: 256 threads / 128 nodes per block (2 threads per node, each does
// half the output columns). Results staged in LDS, then written with a flat
// fully-coalesced uint4/float4 memcpy (LDS layout == global layout).
// Fixes the measured 8x write amplification (WRITE_SIZE 196MB vs 24MB useful:
// old code stored 4-8B per lane at 80/160B stride -> one dirty sector per op).
__global__ void pre1(const float* __restrict__ x, const float* __restrict__ W1l,
                     const float* __restrict__ W1r, const float* __restrict__ b1,
                     u32* __restrict__ xl, float* __restrict__ xr, int n) {
    __shared__ __align__(16) u32   xl_s[128 * (D_H / 2)];   // 10 KB
    __shared__ __align__(16) float xr_s[128 * D_H];         // 20 KB
    int tx = threadIdx.x;
    int m  = tx >> 1;            // local node 0..127
    int t  = tx & 1;             // half selector
    int node = blockIdx.x * 128 + m;
    if (node < n) {
        float4 xv[16];
        const float4* xp = (const float4*)(x + (size_t)node * D_IN);
        #pragma unroll
        for (int k = 0; k < 16; ++k) xv[k] = xp[k];
        #pragma unroll
        for (int k = 0; k < 10; ++k) {
            int o = t * 20 + 2 * k;
            float al0 = dot16((const float4*)(W1l + o * D_IN), xv);
            float al1 = dot16((const float4*)(W1l + (o + 1) * D_IN), xv);
            float ar0 = dot16((const float4*)(W1r + o * D_IN), xv);
            float ar1 = dot16((const float4*)(W1r + (o + 1) * D_IN), xv);
            xl_s[m * (D_H / 2) + (o >> 1)] =
                (u32)f32_to_bf16_rne(al0) | ((u32)f32_to_bf16_rne(al1) << 16);
            xr_s[m * D_H + o]     = ar0 + b1[o];
            xr_s[m * D_H + o + 1] = ar1 + b1[o + 1];
        }
    }
    __syncthreads();
    int nb = min(128, n - blockIdx.x * 128);     // nodes in this block
    // xl: nb*20 u32 = nb*5 uint4 (always divisible)
    const uint4* sl = (const uint4*)xl_s;
    uint4* gl = (uint4*)(xl + (size_t)blockIdx.x * 128 * (D_H / 2));
    for (int i = tx; i < nb * 5; i += 256) gl[i] = sl[i];
    // xr: nb*40 f32 = nb*10 float4
    const float4* sr = (const float4*)xr_s;
    float4* gr = (float4*)(xr + (size_t)blockIdx.x * 128 * D_H);
    for (int i = tx; i < nb * 10; i += 256) gr[i] = sr[i];
}

// ---------------- Layer 1: h = relu(mean_gather(xl) + xr), in-place on xr ----
__global__ void gather_node1(const u32* __restrict__ xlp,
                             const int* __restrict__ off,
                             const int* __restrict__ csr,
                             float* __restrict__ hbuf,  // xr in, h out (n x 40)
                             int n) {
    __shared__ __align__(16) float part[4][12][D_H];
    int local = threadIdx.x >> 6;
    int lane  = threadIdx.x & 63;
    int node  = blockIdx.x * 4 + local;
    int g = lane / 5;
    int t = lane - g * 5;
    int deg = 0;
    const uint4* rows = (const uint4*)xlp;   // 5 uint4 per row
    if (node < n) {
        int o0 = off[node], o1 = off[node + 1];
        deg = o1 - o0;
        float a0[8] = {0,0,0,0,0,0,0,0};
        float a1[8] = {0,0,0,0,0,0,0,0};
        float a2[8] = {0,0,0,0,0,0,0,0};
        float a3[8] = {0,0,0,0,0,0,0,0};
        for (int base = o0; base < o1; base += 64) {
            int cnt = min(64, o1 - base);
            int idx = (base + lane < o1) ? csr[base + lane] : 0;
            if (g < 12) {
                for (int j = 0; j < cnt; j += 48) {
                    int j0 = j + g, j1 = j + 12 + g, j2 = j + 24 + g, j3 = j + 36 + g;
                    int s0 = __shfl(idx, j0 & 63);
                    int s1 = __shfl(idx, j1 & 63);
                    int s2 = __shfl(idx, j2 & 63);
                    int s3 = __shfl(idx, j3 & 63);
                    // Clamp out-of-range slots onto s0's row (dup loads coalesce
                    // in L1/MSHR -> no extra L2/L3 traffic, MLP preserved).
                    if (j1 >= cnt) s1 = s0;
                    if (j2 >= cnt) s2 = s0;
                    if (j3 >= cnt) s3 = s0;
                    uint4 w0 = rows[(size_t)s0 * 5 + t];
                    uint4 w1 = rows[(size_t)s1 * 5 + t];
                    uint4 w2 = rows[(size_t)s2 * 5 + t];
                    uint4 w3 = rows[(size_t)s3 * 5 + t];
                    if (j0 < cnt) accum8(a0, w0);
                    if (j1 < cnt) accum8(a1, w1);
                    if (j2 < cnt) accum8(a2, w2);
                    if (j3 < cnt) accum8(a3, w3);
                }
            }
        }
        if (g < 12) {
            #pragma unroll
            for (int k = 0; k < 8; ++k) a0[k] += a1[k] + a2[k] + a3[k];
            float* p = &part[local][g][t * 8];
            ((float4*)p)[0] = make_float4(a0[0], a0[1], a0[2], a0[3]);
            ((float4*)p)[1] = make_float4(a0[4], a0[5], a0[6], a0[7]);
        }
    }
    __syncthreads();
    if (node < n && lane < D_H) {
        float inv = 1.0f / fmaxf((float)deg, 1.0f);
        float agg = 0.0f;
        #pragma unroll
        for (int gg = 0; gg < 12; ++gg) agg += part[local][gg][lane];
        size_t p = (size_t)node * D_H + lane;
        hbuf[p] = fmaxf(agg * inv + hbuf[p], 0.0f);
    }
}

// ---------------- pre2: h2 = bf16(h@W2l^T) compact; hr = h@W2r^T + b2 --------
// Same LDS-staged coalesced-write structure as pre1. hr stays in-place
// (stride-40 rows, first 24 floats) but is emitted as contiguous 96B row
// bursts from LDS (~1.3x amp instead of ~5x from scattered float2 stores).
__global__ void pre2(float* __restrict__ hbuf, const float* __restrict__ W2l,
                     const float* __restrict__ W2r, const float* __restrict__ b2,
                     u32* __restrict__ h2, int n) {
    __shared__ __align__(16) u32   h2_s[128 * (D_OUT / 2)];  // 6 KB
    __shared__ __align__(16) float hr_s[128 * D_OUT];        // 12 KB
    int tx = threadIdx.x;
    int m  = tx >> 1;
    int t  = tx & 1;
    int node = blockIdx.x * 128 + m;
    if (node < n) {
        float4 hv[10];
        const float4* hp = (const float4*)(hbuf + (size_t)node * D_H);
        #pragma unroll
        for (int k = 0; k < 10; ++k) hv[k] = hp[k];
        #pragma unroll
        for (int k = 0; k < 6; ++k) {
            int o = t * 12 + 2 * k;
            float al0 = dot10((const float4*)(W2l + o * D_H), hv);
            float al1 = dot10((const float4*)(W2l + (o + 1) * D_H), hv);
            float ar0 = dot10((const float4*)(W2r + o * D_H), hv);
            float ar1 = dot10((const float4*)(W2r + (o + 1) * D_H), hv);
            h2_s[m * (D_OUT / 2) + (o >> 1)] =
                (u32)f32_to_bf16_rne(al0) | ((u32)f32_to_bf16_rne(al1) << 16);
            hr_s[m * D_OUT + o]     = ar0 + b2[o];
            hr_s[m * D_OUT + o + 1] = ar1 + b2[o + 1];
        }
    }
    __syncthreads();
    int nb = min(128, n - blockIdx.x * 128);
    // h2: nb*12 u32 = nb*3 uint4
    const uint4* sl = (const uint4*)h2_s;
    uint4* gl = (uint4*)(h2 + (size_t)blockIdx.x * 128 * (D_OUT / 2));
    for (int i = tx; i < nb * 3; i += 256) gl[i] = sl[i];
    // hr: rows of 24 f32 into stride-40 rows; float2 granularity, row bursts.
    const float2* sr = (const float2*)hr_s;
    float* grow = hbuf + (size_t)blockIdx.x * 128 * D_H;
    for (int i = tx; i < nb * 12; i += 256) {
        int nl = i / 12, c2 = i - nl * 12;
        *(float2*)(grow + (size_t)nl * D_H + c2 * 2) = sr[i];
    }
}

// ---------------- Layer 2: out = log_softmax(mean_gather(h2) + hr) -----------
__global__ void gather_node2(const u32* __restrict__ h2p,
                             const int* __restrict__ off,
                             const int* __restrict__ csr,
                             const float* __restrict__ hbuf,  // hr rows (stride 40)
                             float* __restrict__ out, int n) {
    __shared__ __align__(16) float part[4][21][D_OUT];
    int local = threadIdx.x >> 6;
    int lane  = threadIdx.x & 63;
    int node  = blockIdx.x * 4 + local;
    int g = lane / 3;
    int t = lane - g * 3;
    int deg = 0;
    const uint4* rows = (const uint4*)h2p;   // 3 uint4 per row
    if (node < n) {
        int o0 = off[node], o1 = off[node + 1];
        deg = o1 - o0;
        float a0[8] = {0,0,0,0,0,0,0,0};
        float a1[8] = {0,0,0,0,0,0,0,0};
        for (int base = o0; base < o1; base += 64) {
            int cnt = min(64, o1 - base);
            int idx = (base + lane < o1) ? csr[base + lane] : 0;
            if (g < 21) {
                for (int j = 0; j < cnt; j += 42) {
                    int j0 = j + g, j1 = j + 21 + g;
                    int s0 = __shfl(idx, j0 & 63);
                    int s1 = __shfl(idx, j1 & 63);
                    // Same clamp trick as gather_node1: dup load hits s0's line.
                    if (j1 >= cnt) s1 = s0;
                    uint4 w0 = rows[(size_t)s0 * 3 + t];
                    uint4 w1 = rows[(size_t)s1 * 3 + t];
                    if (j0 < cnt) accum8(a0, w0);
                    if (j1 < cnt) accum8(a1, w1);
                }
            }
        }
        if (g < 21) {
            #pragma unroll
            for (int k = 0; k < 8; ++k) a0[k] += a1[k];
            float* p = &part[local][g][t * 8];
            ((float4*)p)[0] = make_float4(a0[0], a0[1], a0[2], a0[3]);
            ((float4*)p)[1] = make_float4(a0[4], a0[5], a0[6], a0[7]);
        }
    }
    __syncthreads();
    // Wave-parallel log_softmax: lane k (k<24) holds its own logit in a register;
    // 32-wide butterfly for max and sum (lanes 24..31 seeded -INF / 0).
    float val = 0.0f;
    if (node < n && lane < D_OUT) {
        float inv = 1.0f / fmaxf((float)deg, 1.0f);
        float agg = 0.0f;
        #pragma unroll
        for (int gg = 0; gg < 21; ++gg) agg += part[local][gg][lane];
        val = agg * inv + hbuf[(size_t)node * D_H + lane];
    }
    float m = (lane < D_OUT) ? val : -INFINITY;
    #pragma unroll
    for (int d = 16; d >= 1; d >>= 1) m = fmaxf(m, __shfl_xor(m, d, 32));
    float e = (lane < D_OUT) ? expf(val - m) : 0.0f;
    float se = e;
    #pragma unroll
    for (int d = 16; d >= 1; d >>= 1) se += __shfl_xor(se, d, 32);
    if (node < n && lane < D_OUT)
        out[(size_t)node * D_OUT + lane] = val - m - logf(se);
}

extern "C" void kernel_launch(void* const* d_in, const int* in_sizes, int n_in,
                              void* d_out, int out_size, void* d_ws, size_t ws_size,
                              hipStream_t stream) {
    const float* x   = (const float*)d_in[0];
    const int*   ei  = (const int*)d_in[1];
    const float* W1l = (const float*)d_in[2];
    const float* b1  = (const float*)d_in[3];
    const float* W1r = (const float*)d_in[4];
    const float* W2l = (const float*)d_in[5];
    const float* b2  = (const float*)d_in[6];
    const float* W2r = (const float*)d_in[7];
    float* out = (float*)d_out;

    const int n = in_sizes[0] / D_IN;      // 100000
    const int E = in_sizes[1] / 2;         // 3200000
    const int* src = ei;
    const int* dst = ei + E;

    const int B   = (n + S_NODES - 1) >> S_BITS;   // 391 buckets
    const int NB1 = (E + CH - 1) / CH;             // 391 edge blocks

    // Workspace (~38 MB):
    //  region0: n*40 f32 = 16 MB — bucketed (E u32, 12.8MB) then xr/h/hr (buf0)
    //  xl : n*40 bf16 = 8 MB — xl then h2 (compact n*24 bf16)
    //  off: (n+1) i32
    //  G  : NB1*B i32 ≈ 0.61 MB
    //  bktTotal: B i32 ; bktStart: (B+1) i32
    //  csr: E i32 = 12.8 MB
    char* ws = (char*)d_ws;
    float* buf0     = (float*)ws;
    u32*   bucketed = (u32*)ws;      ws += (size_t)n * D_H * 4;
    u16*   xl       = (u16*)ws;
    u16*   h2       = (u16*)ws;      ws += (size_t)n * D_H * 2;
    int*   off      = (int*)ws;      ws += (((size_t)(n + 1) * 4 + 15) & ~15ull);
    int*   G        = (int*)ws;      ws += (((size_t)NB1 * B * 4 + 15) & ~15ull);
    int*   bktTotal = (int*)ws;      ws += (((size_t)B * 4 + 15) & ~15ull);
    int*   bktStart = (int*)ws;      ws += (((size_t)(B + 1) * 4 + 15) & ~15ull);
    int*   csr      = (int*)ws;

    passA<<<NB1, 256, 0, stream>>>(dst, G, E, B);
    colscan<<<B, 64, 0, stream>>>(G, bktTotal, NB1, B);
    bucketscan<<<1, 64, 0, stream>>>(bktTotal, bktStart, off, B, E, n);
    passB<<<NB1, 256, 0, stream>>>(src, dst, G, bktStart, bucketed, E, B);
    bucket_csr<<<B, 256, 0, stream>>>(bucketed, bktStart, off, csr, n);

    pre1<<<(n + 127) / 128, 256, 0, stream>>>(x, W1l, W1r, b1, (u32*)xl, buf0, n);
    gather_node1<<<(n + 3) / 4, 256, 0, stream>>>((const u32*)xl, off, csr, buf0, n);
    pre2<<<(n + 127) / 128, 256, 0, stream>>>(buf0, W2l, W2r, b2, (u32*)h2, n);
    gather_node2<<<(n + 3) / 4, 256, 0, stream>>>((const u32*)h2, off, csr, buf0, out, n);
}

// Round 5
// 457.046 us; speedup vs baseline: 1.2579x; 1.2579x over previous
//
#include <hip/hip_runtime.h>
#include <math.h>

#define D_IN 64
#define D_H 40
#define D_OUT 24
#define S_BITS 8
#define S_NODES 256      // nodes per bucket
#define CH 8192          // edges per passA/passB block
#define BMAX 512         // max buckets (n <= 131072)

typedef unsigned int u32;
typedef unsigned short u16;

// ---------------- CSR build: atomic-free LDS multisplit ----------------
// passA: per-block histogram of dst buckets (bucket = dst >> 8).
// int4-vectorized edge reads: 4 edges/thread/iter, 1KB/wave-instr.
__global__ void passA(const int* __restrict__ dst, int* __restrict__ G,
                      int E, int B) {
    __shared__ int hist[BMAX];
    int tx = threadIdx.x;
    for (int i = tx; i < B; i += 256) hist[i] = 0;
    __syncthreads();
    int e0 = blockIdx.x * CH;
    int e1 = min(e0 + CH, E);
    for (int e = e0 + tx * 4; e < e1; e += 1024) {
        if (e + 4 <= e1) {
            int4 d4 = *(const int4*)(dst + e);
            atomicAdd(&hist[d4.x >> S_BITS], 1);
            atomicAdd(&hist[d4.y >> S_BITS], 1);
            atomicAdd(&hist[d4.z >> S_BITS], 1);
            atomicAdd(&hist[d4.w >> S_BITS], 1);
        } else {
            for (int q = e; q < e1; ++q)
                atomicAdd(&hist[dst[q] >> S_BITS], 1);
        }
    }
    __syncthreads();
    for (int i = tx; i < B; i += 256) G[(size_t)blockIdx.x * B + i] = hist[i];
}

// colscan: for bucket b, exclusive-scan G[i][b] over blocks i; total -> bktTotal.
__global__ void colscan(int* __restrict__ G, int* __restrict__ bktTotal,
                        int NB1, int B) {
    int b = blockIdx.x;
    int lane = threadIdx.x;      // 64 threads
    int carry = 0;
    for (int base = 0; base < NB1; base += 64) {
        int i = base + lane;
        int orig = (i < NB1) ? G[(size_t)i * B + b] : 0;
        int v = orig;
        #pragma unroll
        for (int d = 1; d < 64; d <<= 1) {
            int t = __shfl_up(v, d);
            if (lane >= d) v += t;
        }
        if (i < NB1) G[(size_t)i * B + b] = carry + v - orig;   // exclusive
        carry += __shfl(v, 63);
    }
    if (lane == 0) bktTotal[b] = carry;
}

// bucketscan: exclusive scan of bucket totals -> bktStart[0..B]; off[n] = E.
__global__ void bucketscan(const int* __restrict__ bktTotal,
                           int* __restrict__ bktStart, int* __restrict__ off,
                           int B, int E, int n) {
    int lane = threadIdx.x;
    int carry = 0;
    for (int base = 0; base < B; base += 64) {
        int i = base + lane;
        int orig = (i < B) ? bktTotal[i] : 0;
        int v = orig;
        #pragma unroll
        for (int d = 1; d < 64; d <<= 1) {
            int t = __shfl_up(v, d);
            if (lane >= d) v += t;
        }
        if (i < B) bktStart[i] = carry + v - orig;
        carry += __shfl(v, 63);
    }
    if (lane == 0) { bktStart[B] = carry; off[n] = E; }
}

// passB: scatter edges into bucket-major order, packed (dstl<<24 | src).
// int4-vectorized src/dst reads; scatter stores unchanged (bucket content is
// order-insensitive: per-node ranks were already atomic-race-ordered).
__global__ void passB(const int* __restrict__ src, const int* __restrict__ dst,
                      const int* __restrict__ G, const int* __restrict__ bktStart,
                      u32* __restrict__ bucketed, int E, int B) {
    __shared__ int baseS[BMAX];
    __shared__ int cnt[BMAX];
    int tx = threadIdx.x;
    for (int i = tx; i < B; i += 256) {
        baseS[i] = bktStart[i] + G[(size_t)blockIdx.x * B + i];
        cnt[i] = 0;
    }
    __syncthreads();
    int e0 = blockIdx.x * CH;
    int e1 = min(e0 + CH, E);
    for (int e = e0 + tx * 4; e < e1; e += 1024) {
        if (e + 4 <= e1) {
            int4 d4 = *(const int4*)(dst + e);
            int4 s4 = *(const int4*)(src + e);
            int b0 = d4.x >> S_BITS, b1 = d4.y >> S_BITS;
            int b2 = d4.z >> S_BITS, b3 = d4.w >> S_BITS;
            int r0 = atomicAdd(&cnt[b0], 1);
            int r1 = atomicAdd(&cnt[b1], 1);
            int r2 = atomicAdd(&cnt[b2], 1);
            int r3 = atomicAdd(&cnt[b3], 1);
            bucketed[baseS[b0] + r0] = ((u32)(d4.x & (S_NODES - 1)) << 24) | (u32)s4.x;
            bucketed[baseS[b1] + r1] = ((u32)(d4.y & (S_NODES - 1)) << 24) | (u32)s4.y;
            bucketed[baseS[b2] + r2] = ((u32)(d4.z & (S_NODES - 1)) << 24) | (u32)s4.z;
            bucketed[baseS[b3] + r3] = ((u32)(d4.w & (S_NODES - 1)) << 24) | (u32)s4.w;
        } else {
            for (int q = e; q < e1; ++q) {
                int d = dst[q];
                int b = d >> S_BITS;
                int r = atomicAdd(&cnt[b], 1);
                bucketed[baseS[b] + r] = ((u32)(d & (S_NODES - 1)) << 24) | (u32)src[q];
            }
        }
    }
}

// bucket_csr: one block per bucket. Count 256 local nodes, LDS scan -> off,
// then rank+place into final CSR. No global scan, no global atomics.
__global__ void bucket_csr(const u32* __restrict__ bucketed,
                           const int* __restrict__ bktStart,
                           int* __restrict__ off, int* __restrict__ csr,
                           int n) {
    __shared__ int degl[S_NODES];
    __shared__ int offl[S_NODES + 1];
    __shared__ int cntl[S_NODES];
    int b  = blockIdx.x;
    int tx = threadIdx.x;        // 256
    int bs = bktStart[b], be = bktStart[b + 1];
    degl[tx] = 0;
    cntl[tx] = 0;
    __syncthreads();
    for (int e = bs + tx; e < be; e += 256)
        atomicAdd(&degl[bucketed[e] >> 24], 1);      // LDS atomic
    __syncthreads();
    int v = degl[tx];
    offl[tx] = v;
    __syncthreads();
    for (int d = 1; d < 256; d <<= 1) {              // Hillis-Steele inclusive
        int t = (tx >= d) ? offl[tx - d] : 0;
        __syncthreads();
        offl[tx] += t;
        __syncthreads();
    }
    int excl = offl[tx] - v;
    __syncthreads();
    offl[tx] = excl;
    if (tx == 255) offl[256] = excl + v;
    __syncthreads();
    int node = b * S_NODES + tx;
    if (node <= n) off[node] = bs + offl[tx];
    for (int e = bs + tx; e < be; e += 256) {
        u32 w = bucketed[e];
        int dl = w >> 24;
        int r = atomicAdd(&cntl[dl], 1);             // LDS atomic
        csr[bs + offl[dl] + r] = (int)(w & 0xFFFFFFu);
    }
}

// ---------------- bf16 helpers ----------------
__device__ inline u16 f32_to_bf16_rne(float f) {
    u32 u = __float_as_uint(f);
    u += 0x7fffu + ((u >> 16) & 1u);
    return (u16)(u >> 16);
}

__device__ inline void accum8(float* a, uint4 w) {
    a[0] += __uint_as_float(w.x << 16);
    a[1] += __uint_as_float(w.x & 0xffff0000u);
    a[2] += __uint_as_float(w.y << 16);
    a[3] += __uint_as_float(w.y & 0xffff0000u);
    a[4] += __uint_as_float(w.z << 16);
    a[5] += __uint_as_float(w.z & 0xffff0000u);
    a[6] += __uint_as_float(w.w << 16);
    a[7] += __uint_as_float(w.w & 0xffff0000u);
}

__device__ inline float dot16(const float4* __restrict__ w, const float4* v) {
    float acc = 0.0f;
    #pragma unroll
    for (int k = 0; k < 16; ++k) {
        float4 a = w[k], b = v[k];
        acc += a.x * b.x + a.y * b.y + a.z * b.z + a.w * b.w;
    }
    return acc;
}

__device__ inline float dot10(const float4* __restrict__ w, const float4* v) {
    float acc = 0.0f;
    #pragma unroll
    for (int k = 0; k < 10; ++k) {
        float4 a = w[k], b = v[k];
        acc += a.x * b.x + a.y * b.y + a.z * b.z + a.w * b.w;
    }
    return acc;
}

// ---------------- pre1: xl = bf16(x@W1l^T), xr = x@W1r^T + b1 ----------------
// LDS-staged coalesced writeout (round 3) + __launch_bounds__(256) (round 4):
// without launch bounds the compiler capped at 64 VGPRs and SPILLED xv[16]
// (64 regs) to scratch -> 268MB HBM FETCH / 125MB excess WRITE measured.
// 256-thread bound raises the VGPR budget so the row stays in registers.
__global__ __launch_bounds__(256)
void pre1(const float* __restrict__ x, const float* __restrict__ W1l,
          const float* __restrict__ W1r, const float* __restrict__ b1,
          u32* __restrict__ xl, float* __restrict__ xr, int n) {
    __shared__ __align__(16) u32   xl_s[128 * (D_H / 2)];   // 10 KB
    __shared__ __align__(16) float xr_s[128 * D_H];         // 20 KB
    int tx = threadIdx.x;
    int m  = tx >> 1;            // local node 0..127
    int t  = tx & 1;             // half selector
    int node = blockIdx.x * 128 + m;
    if (node < n) {
        float4 xv[16];
        const float4* xp = (const float4*)(x + (size_t)node * D_IN);
        #pragma unroll
        for (int k = 0; k < 16; ++k) xv[k] = xp[k];
        #pragma unroll
        for (int k = 0; k < 10; ++k) {
            int o = t * 20 + 2 * k;
            float al0 = dot16((const float4*)(W1l + o * D_IN), xv);
            float al1 = dot16((const float4*)(W1l + (o + 1) * D_IN), xv);
            float ar0 = dot16((const float4*)(W1r + o * D_IN), xv);
            float ar1 = dot16((const float4*)(W1r + (o + 1) * D_IN), xv);
            xl_s[m * (D_H / 2) + (o >> 1)] =
                (u32)f32_to_bf16_rne(al0) | ((u32)f32_to_bf16_rne(al1) << 16);
            xr_s[m * D_H + o]     = ar0 + b1[o];
            xr_s[m * D_H + o + 1] = ar1 + b1[o + 1];
        }
    }
    __syncthreads();
    int nb = min(128, n - blockIdx.x * 128);     // nodes in this block
    // xl: nb*20 u32 = nb*5 uint4 (always divisible)
    const uint4* sl = (const uint4*)xl_s;
    uint4* gl = (uint4*)(xl + (size_t)blockIdx.x * 128 * (D_H / 2));
    for (int i = tx; i < nb * 5; i += 256) gl[i] = sl[i];
    // xr: nb*40 f32 = nb*10 float4
    const float4* sr = (const float4*)xr_s;
    float4* gr = (float4*)(xr + (size_t)blockIdx.x * 128 * D_H);
    for (int i = tx; i < nb * 10; i += 256) gr[i] = sr[i];
}

// ---------------- Layer 1: h = relu(mean_gather(xl) + xr), in-place on xr ----
__global__ void gather_node1(const u32* __restrict__ xlp,
                             const int* __restrict__ off,
                             const int* __restrict__ csr,
                             float* __restrict__ hbuf,  // xr in, h out (n x 40)
                             int n) {
    __shared__ __align__(16) float part[4][12][D_H];
    int local = threadIdx.x >> 6;
    int lane  = threadIdx.x & 63;
    int node  = blockIdx.x * 4 + local;
    int g = lane / 5;
    int t = lane - g * 5;
    int deg = 0;
    const uint4* rows = (const uint4*)xlp;   // 5 uint4 per row
    if (node < n) {
        int o0 = off[node], o1 = off[node + 1];
        deg = o1 - o0;
        float a0[8] = {0,0,0,0,0,0,0,0};
        float a1[8] = {0,0,0,0,0,0,0,0};
        float a2[8] = {0,0,0,0,0,0,0,0};
        float a3[8] = {0,0,0,0,0,0,0,0};
        for (int base = o0; base < o1; base += 64) {
            int cnt = min(64, o1 - base);
            int idx = (base + lane < o1) ? csr[base + lane] : 0;
            if (g < 12) {
                for (int j = 0; j < cnt; j += 48) {
                    int j0 = j + g, j1 = j + 12 + g, j2 = j + 24 + g, j3 = j + 36 + g;
                    int s0 = __shfl(idx, j0 & 63);
                    int s1 = __shfl(idx, j1 & 63);
                    int s2 = __shfl(idx, j2 & 63);
                    int s3 = __shfl(idx, j3 & 63);
                    // Clamp out-of-range slots onto s0's row (dup loads coalesce
                    // in L1/MSHR -> no extra L2/L3 traffic, MLP preserved).
                    if (j1 >= cnt) s1 = s0;
                    if (j2 >= cnt) s2 = s0;
                    if (j3 >= cnt) s3 = s0;
                    uint4 w0 = rows[(size_t)s0 * 5 + t];
                    uint4 w1 = rows[(size_t)s1 * 5 + t];
                    uint4 w2 = rows[(size_t)s2 * 5 + t];
                    uint4 w3 = rows[(size_t)s3 * 5 + t];
                    if (j0 < cnt) accum8(a0, w0);
                    if (j1 < cnt) accum8(a1, w1);
                    if (j2 < cnt) accum8(a2, w2);
                    if (j3 < cnt) accum8(a3, w3);
                }
            }
        }
        if (g < 12) {
            #pragma unroll
            for (int k = 0; k < 8; ++k) a0[k] += a1[k] + a2[k] + a3[k];
            float* p = &part[local][g][t * 8];
            ((float4*)p)[0] = make_float4(a0[0], a0[1], a0[2], a0[3]);
            ((float4*)p)[1] = make_float4(a0[4], a0[5], a0[6], a0[7]);
        }
    }
    __syncthreads();
    if (node < n && lane < D_H) {
        float inv = 1.0f / fmaxf((float)deg, 1.0f);
        float agg = 0.0f;
        #pragma unroll
        for (int gg = 0; gg < 12; ++gg) agg += part[local][gg][lane];
        size_t p = (size_t)node * D_H + lane;
        hbuf[p] = fmaxf(agg * inv + hbuf[p], 0.0f);
    }
}

// ---------------- pre2: h2 = bf16(h@W2l^T) compact; hr = h@W2r^T + b2 --------
// Same LDS-staged coalesced-write structure as pre1, same launch bounds fix.
__global__ __launch_bounds__(256)
void pre2(float* __restrict__ hbuf, const float* __restrict__ W2l,
          const float* __restrict__ W2r, const float* __restrict__ b2,
          u32* __restrict__ h2, int n) {
    __shared__ __align__(16) u32   h2_s[128 * (D_OUT / 2)];  // 6 KB
    __shared__ __align__(16) float hr_s[128 * D_OUT];        // 12 KB
    int tx = threadIdx.x;
    int m  = tx >> 1;
    int t  = tx & 1;
    int node = blockIdx.x * 128 + m;
    if (node < n) {
        float4 hv[10];
        const float4* hp = (const float4*)(hbuf + (size_t)node * D_H);
        #pragma unroll
        for (int k = 0; k < 10; ++k) hv[k] = hp[k];
        #pragma unroll
        for (int k = 0; k < 6; ++k) {
            int o = t * 12 + 2 * k;
            float al0 = dot10((const float4*)(W2l + o * D_H), hv);
            float al1 = dot10((const float4*)(W2l + (o + 1) * D_H), hv);
            float ar0 = dot10((const float4*)(W2r + o * D_H), hv);
            float ar1 = dot10((const float4*)(W2r + (o + 1) * D_H), hv);
            h2_s[m * (D_OUT / 2) + (o >> 1)] =
                (u32)f32_to_bf16_rne(al0) | ((u32)f32_to_bf16_rne(al1) << 16);
            hr_s[m * D_OUT + o]     = ar0 + b2[o];
            hr_s[m * D_OUT + o + 1] = ar1 + b2[o + 1];
        }
    }
    __syncthreads();
    int nb = min(128, n - blockIdx.x * 128);
    // h2: nb*12 u32 = nb*3 uint4
    const uint4* sl = (const uint4*)h2_s;
    uint4* gl = (uint4*)(h2 + (size_t)blockIdx.x * 128 * (D_OUT / 2));
    for (int i = tx; i < nb * 3; i += 256) gl[i] = sl[i];
    // hr: rows of 24 f32 into stride-40 rows; float2 granularity, row bursts.
    const float2* sr = (const float2*)hr_s;
    float* grow = hbuf + (size_t)blockIdx.x * 128 * D_H;
    for (int i = tx; i < nb * 12; i += 256) {
        int nl = i / 12, c2 = i - nl * 12;
        *(float2*)(grow + (size_t)nl * D_H + c2 * 2) = sr[i];
    }
}

// ---------------- Layer 2: out = log_softmax(mean_gather(h2) + hr) -----------
__global__ void gather_node2(const u32* __restrict__ h2p,
                             const int* __restrict__ off,
                             const int* __restrict__ csr,
                             const float* __restrict__ hbuf,  // hr rows (stride 40)
                             float* __restrict__ out, int n) {
    __shared__ __align__(16) float part[4][21][D_OUT];
    int local = threadIdx.x >> 6;
    int lane  = threadIdx.x & 63;
    int node  = blockIdx.x * 4 + local;
    int g = lane / 3;
    int t = lane - g * 3;
    int deg = 0;
    const uint4* rows = (const uint4*)h2p;   // 3 uint4 per row
    if (node < n) {
        int o0 = off[node], o1 = off[node + 1];
        deg = o1 - o0;
        float a0[8] = {0,0,0,0,0,0,0,0};
        float a1[8] = {0,0,0,0,0,0,0,0};
        for (int base = o0; base < o1; base += 64) {
            int cnt = min(64, o1 - base);
            int idx = (base + lane < o1) ? csr[base + lane] : 0;
            if (g < 21) {
                for (int j = 0; j < cnt; j += 42) {
                    int j0 = j + g, j1 = j + 21 + g;
                    int s0 = __shfl(idx, j0 & 63);
                    int s1 = __shfl(idx, j1 & 63);
                    // Same clamp trick as gather_node1: dup load hits s0's line.
                    if (j1 >= cnt) s1 = s0;
                    uint4 w0 = rows[(size_t)s0 * 3 + t];
                    uint4 w1 = rows[(size_t)s1 * 3 + t];
                    if (j0 < cnt) accum8(a0, w0);
                    if (j1 < cnt) accum8(a1, w1);
                }
            }
        }
        if (g < 21) {
            #pragma unroll
            for (int k = 0; k < 8; ++k) a0[k] += a1[k];
            float* p = &part[local][g][t * 8];
            ((float4*)p)[0] = make_float4(a0[0], a0[1], a0[2], a0[3]);
            ((float4*)p)[1] = make_float4(a0[4], a0[5], a0[6], a0[7]);
        }
    }
    __syncthreads();
    // Wave-parallel log_softmax: lane k (k<24) holds its own logit in a register;
    // 32-wide butterfly for max and sum (lanes 24..31 seeded -INF / 0).
    float val = 0.0f;
    if (node < n && lane < D_OUT) {
        float inv = 1.0f / fmaxf((float)deg, 1.0f);
        float agg = 0.0f;
        #pragma unroll
        for (int gg = 0; gg < 21; ++gg) agg += part[local][gg][lane];
        val = agg * inv + hbuf[(size_t)node * D_H + lane];
    }
    float m = (lane < D_OUT) ? val : -INFINITY;
    #pragma unroll
    for (int d = 16; d >= 1; d >>= 1) m = fmaxf(m, __shfl_xor(m, d, 32));
    float e = (lane < D_OUT) ? expf(val - m) : 0.0f;
    float se = e;
    #pragma unroll
    for (int d = 16; d >= 1; d >>= 1) se += __shfl_xor(se, d, 32);
    if (node < n && lane < D_OUT)
        out[(size_t)node * D_OUT + lane] = val - m - logf(se);
}

extern "C" void kernel_launch(void* const* d_in, const int* in_sizes, int n_in,
                              void* d_out, int out_size, void* d_ws, size_t ws_size,
                              hipStream_t stream) {
    const float* x   = (const float*)d_in[0];
    const int*   ei  = (const int*)d_in[1];
    const float* W1l = (const float*)d_in[2];
    const float* b1  = (const float*)d_in[3];
    const float* W1r = (const float*)d_in[4];
    const float* W2l = (const float*)d_in[5];
    const float* b2  = (const float*)d_in[6];
    const float* W2r = (const float*)d_in[7];
    float* out = (float*)d_out;

    const int n = in_sizes[0] / D_IN;      // 100000
    const int E = in_sizes[1] / 2;         // 3200000
    const int* src = ei;
    const int* dst = ei + E;

    const int B   = (n + S_NODES - 1) >> S_BITS;   // 391 buckets
    const int NB1 = (E + CH - 1) / CH;             // 391 edge blocks

    // Workspace (~38 MB):
    //  region0: n*40 f32 = 16 MB — bucketed (E u32, 12.8MB) then xr/h/hr (buf0)
    //  xl : n*40 bf16 = 8 MB — xl then h2 (compact n*24 bf16)
    //  off: (n+1) i32
    //  G  : NB1*B i32 ≈ 0.61 MB
    //  bktTotal: B i32 ; bktStart: (B+1) i32
    //  csr: E i32 = 12.8 MB
    char* ws = (char*)d_ws;
    float* buf0     = (float*)ws;
    u32*   bucketed = (u32*)ws;      ws += (size_t)n * D_H * 4;
    u16*   xl       = (u16*)ws;
    u16*   h2       = (u16*)ws;      ws += (size_t)n * D_H * 2;
    int*   off      = (int*)ws;      ws += (((size_t)(n + 1) * 4 + 15) & ~15ull);
    int*   G        = (int*)ws;      ws += (((size_t)NB1 * B * 4 + 15) & ~15ull);
    int*   bktTotal = (int*)ws;      ws += (((size_t)B * 4 + 15) & ~15ull);
    int*   bktStart = (int*)ws;      ws += (((size_t)(B + 1) * 4 + 15) & ~15ull);
    int*   csr      = (int*)ws;

    passA<<<NB1, 256, 0, stream>>>(dst, G, E, B);
    colscan<<<B, 64, 0, stream>>>(G, bktTotal, NB1, B);
    bucketscan<<<1, 64, 0, stream>>>(bktTotal, bktStart, off, B, E, n);
    passB<<<NB1, 256, 0, stream>>>(src, dst, G, bktStart, bucketed, E, B);
    bucket_csr<<<B, 256, 0, stream>>>(bucketed, bktStart, off, csr, n);

    pre1<<<(n + 127) / 128, 256, 0, stream>>>(x, W1l, W1r, b1, (u32*)xl, buf0, n);
    gather_node1<<<(n + 3) / 4, 256, 0, stream>>>((const u32*)xl, off, csr, buf0, n);
    pre2<<<(n + 127) / 128, 256, 0, stream>>>(buf0, W2l, W2r, b2, (u32*)h2, n);
    gather_node2<<<(n + 3) / 4, 256, 0, stream>>>((const u32*)h2, off, csr, buf0, out, n);
}

// Round 9
// 311.441 us; speedup vs baseline: 1.8461x; 1.4675x over previous
//
#include <hip/hip_runtime.h>
#include <math.h>

#define D_IN 64
#define D_H 40
#define D_OUT 24
#define S_BITS 8
#define S_NODES 256      // nodes per bucket
#define CH 8192          // edges per passA/passB block
#define BMAX 512         // max buckets (n <= 131072)

typedef unsigned int u32;
typedef unsigned short u16;

// ---------------- CSR build: atomic-free LDS multisplit ----------------
// passA: per-block histogram of dst buckets (bucket = dst >> 8).
// int4-vectorized edge reads: 4 edges/thread/iter, 1KB/wave-instr.
__global__ void passA(const int* __restrict__ dst, int* __restrict__ G,
                      int E, int B) {
    __shared__ int hist[BMAX];
    int tx = threadIdx.x;
    for (int i = tx; i < B; i += 256) hist[i] = 0;
    __syncthreads();
    int e0 = blockIdx.x * CH;
    int e1 = min(e0 + CH, E);
    for (int e = e0 + tx * 4; e < e1; e += 1024) {
        if (e + 4 <= e1) {
            int4 d4 = *(const int4*)(dst + e);
            atomicAdd(&hist[d4.x >> S_BITS], 1);
            atomicAdd(&hist[d4.y >> S_BITS], 1);
            atomicAdd(&hist[d4.z >> S_BITS], 1);
            atomicAdd(&hist[d4.w >> S_BITS], 1);
        } else {
            for (int q = e; q < e1; ++q)
                atomicAdd(&hist[dst[q] >> S_BITS], 1);
        }
    }
    __syncthreads();
    for (int i = tx; i < B; i += 256) G[(size_t)blockIdx.x * B + i] = hist[i];
}

// colscan: for bucket b, exclusive-scan G[i][b] over blocks i; total -> bktTotal.
__global__ void colscan(int* __restrict__ G, int* __restrict__ bktTotal,
                        int NB1, int B) {
    int b = blockIdx.x;
    int lane = threadIdx.x;      // 64 threads
    int carry = 0;
    for (int base = 0; base < NB1; base += 64) {
        int i = base + lane;
        int orig = (i < NB1) ? G[(size_t)i * B + b] : 0;
        int v = orig;
        #pragma unroll
        for (int d = 1; d < 64; d <<= 1) {
            int t = __shfl_up(v, d);
            if (lane >= d) v += t;
        }
        if (i < NB1) G[(size_t)i * B + b] = carry + v - orig;   // exclusive
        carry += __shfl(v, 63);
    }
    if (lane == 0) bktTotal[b] = carry;
}

// bucketscan: exclusive scan of bucket totals -> bktStart[0..B]; off[n] = E.
__global__ void bucketscan(const int* __restrict__ bktTotal,
                           int* __restrict__ bktStart, int* __restrict__ off,
                           int B, int E, int n) {
    int lane = threadIdx.x;
    int carry = 0;
    for (int base = 0; base < B; base += 64) {
        int i = base + lane;
        int orig = (i < B) ? bktTotal[i] : 0;
        int v = orig;
        #pragma unroll
        for (int d = 1; d < 64; d <<= 1) {
            int t = __shfl_up(v, d);
            if (lane >= d) v += t;
        }
        if (i < B) bktStart[i] = carry + v - orig;
        carry += __shfl(v, 63);
    }
    if (lane == 0) { bktStart[B] = carry; off[n] = E; }
}

// passB: scatter edges into bucket-major order, packed (dstl<<24 | src).
// int4-vectorized src/dst reads; scatter stores unchanged (bucket content is
// order-insensitive: per-node ranks were already atomic-race-ordered).
__global__ void passB(const int* __restrict__ src, const int* __restrict__ dst,
                      const int* __restrict__ G, const int* __restrict__ bktStart,
                      u32* __restrict__ bucketed, int E, int B) {
    __shared__ int baseS[BMAX];
    __shared__ int cnt[BMAX];
    int tx = threadIdx.x;
    for (int i = tx; i < B; i += 256) {
        baseS[i] = bktStart[i] + G[(size_t)blockIdx.x * B + i];
        cnt[i] = 0;
    }
    __syncthreads();
    int e0 = blockIdx.x * CH;
    int e1 = min(e0 + CH, E);
    for (int e = e0 + tx * 4; e < e1; e += 1024) {
        if (e + 4 <= e1) {
            int4 d4 = *(const int4*)(dst + e);
            int4 s4 = *(const int4*)(src + e);
            int b0 = d4.x >> S_BITS, b1 = d4.y >> S_BITS;
            int b2 = d4.z >> S_BITS, b3 = d4.w >> S_BITS;
            int r0 = atomicAdd(&cnt[b0], 1);
            int r1 = atomicAdd(&cnt[b1], 1);
            int r2 = atomicAdd(&cnt[b2], 1);
            int r3 = atomicAdd(&cnt[b3], 1);
            bucketed[baseS[b0] + r0] = ((u32)(d4.x & (S_NODES - 1)) << 24) | (u32)s4.x;
            bucketed[baseS[b1] + r1] = ((u32)(d4.y & (S_NODES - 1)) << 24) | (u32)s4.y;
            bucketed[baseS[b2] + r2] = ((u32)(d4.z & (S_NODES - 1)) << 24) | (u32)s4.z;
            bucketed[baseS[b3] + r3] = ((u32)(d4.w & (S_NODES - 1)) << 24) | (u32)s4.w;
        } else {
            for (int q = e; q < e1; ++q) {
                int d = dst[q];
                int b = d >> S_BITS;
                int r = atomicAdd(&cnt[b], 1);
                bucketed[baseS[b] + r] = ((u32)(d & (S_NODES - 1)) << 24) | (u32)src[q];
            }
        }
    }
}

// bucket_csr: one block per bucket. Count 256 local nodes, LDS scan -> off,
// then rank+place into final CSR. No global scan, no global atomics.
__global__ void bucket_csr(const u32* __restrict__ bucketed,
                           const int* __restrict__ bktStart,
                           int* __restrict__ off, int* __restrict__ csr,
                           int n) {
    __shared__ int degl[S_NODES];
    __shared__ int offl[S_NODES + 1];
    __shared__ int cntl[S_NODES];
    int b  = blockIdx.x;
    int tx = threadIdx.x;        // 256
    int bs = bktStart[b], be = bktStart[b + 1];
    degl[tx] = 0;
    cntl[tx] = 0;
    __syncthreads();
    for (int e = bs + tx; e < be; e += 256)
        atomicAdd(&degl[bucketed[e] >> 24], 1);      // LDS atomic
    __syncthreads();
    int v = degl[tx];
    offl[tx] = v;
    __syncthreads();
    for (int d = 1; d < 256; d <<= 1) {              // Hillis-Steele inclusive
        int t = (tx >= d) ? offl[tx - d] : 0;
        __syncthreads();
        offl[tx] += t;
        __syncthreads();
    }
    int excl = offl[tx] - v;
    __syncthreads();
    offl[tx] = excl;
    if (tx == 255) offl[256] = excl + v;
    __syncthreads();
    int node = b * S_NODES + tx;
    if (node <= n) off[node] = bs + offl[tx];
    for (int e = bs + tx; e < be; e += 256) {
        u32 w = bucketed[e];
        int dl = w >> 24;
        int r = atomicAdd(&cntl[dl], 1);             // LDS atomic
        csr[bs + offl[dl] + r] = (int)(w & 0xFFFFFFu);
    }
}

// ---------------- bf16 helpers ----------------
__device__ inline u16 f32_to_bf16_rne(float f) {
    u32 u = __float_as_uint(f);
    u += 0x7fffu + ((u >> 16) & 1u);
    return (u16)(u >> 16);
}

__device__ inline void accum8(float* a, uint4 w) {
    a[0] += __uint_as_float(w.x << 16);
    a[1] += __uint_as_float(w.x & 0xffff0000u);
    a[2] += __uint_as_float(w.y << 16);
    a[3] += __uint_as_float(w.y & 0xffff0000u);
    a[4] += __uint_as_float(w.z << 16);
    a[5] += __uint_as_float(w.z & 0xffff0000u);
    a[6] += __uint_as_float(w.w << 16);
    a[7] += __uint_as_float(w.w & 0xffff0000u);
}

__device__ inline float dot16(const float4* __restrict__ w, const float4* v) {
    float acc = 0.0f;
    #pragma unroll
    for (int k = 0; k < 16; ++k) {
        float4 a = w[k], b = v[k];
        acc += a.x * b.x + a.y * b.y + a.z * b.z + a.w * b.w;
    }
    return acc;
}

__device__ inline float dot10(const float4* __restrict__ w, const float4* v) {
    float acc = 0.0f;
    #pragma unroll
    for (int k = 0; k < 10; ++k) {
        float4 a = w[k], b = v[k];
        acc += a.x * b.x + a.y * b.y + a.z * b.z + a.w * b.w;
    }
    return acc;
}

// ---------------- pre1: xl = bf16(x@W1l^T), xr = x@W1r^T + b1 ----------------
// Round 5 counters: spills fixed (FETCH 268->12.8MB) but dur still 154us at
// VALUBusy 10.8% / HBM 3% -> latency-bound on the per-iteration GLOBAL W-row
// loads (320 dwordx4/thread, ~8 in flight, ~3 waves/SIMD -> nothing overlaps).
// Fix: stage W1l|W1r (20.5KB) + b1 in LDS once per block; inner dots read LDS.
// Per ds_read_b128 a wave presents only 2 distinct addresses (one per t half)
// -> broadcast + 2-way, conflict-free. Writeout staging unchanged.
__global__ __launch_bounds__(256)
void pre1(const float* __restrict__ x, const float* __restrict__ W1l,
          const float* __restrict__ W1r, const float* __restrict__ b1,
          u32* __restrict__ xl, float* __restrict__ xr, int n) {
    __shared__ __align__(16) float Ws[80 * D_IN];           // 20.5 KB: rows 0..39=W1l, 40..79=W1r
    __shared__ float b1s[D_H];
    __shared__ __align__(16) u32   xl_s[128 * (D_H / 2)];   // 10 KB
    __shared__ __align__(16) float xr_s[128 * D_H];         // 20 KB
    int tx = threadIdx.x;
    // cooperative W load: 80 rows x 16 float4 = 1280 float4, identity layout
    {
        float4* wd = (float4*)Ws;
        for (int i = tx; i < 80 * 16; i += 256) {
            int r = i >> 4, c = i & 15;
            float4 v = (r < 40) ? ((const float4*)(W1l + r * D_IN))[c]
                                : ((const float4*)(W1r + (r - 40) * D_IN))[c];
            wd[i] = v;
        }
        if (tx < D_H) b1s[tx] = b1[tx];
    }
    __syncthreads();
    int m  = tx >> 1;            // local node 0..127
    int t  = tx & 1;             // half selector
    int node = blockIdx.x * 128 + m;
    if (node < n) {
        float4 xv[16];
        const float4* xp = (const float4*)(x + (size_t)node * D_IN);
        #pragma unroll
        for (int k = 0; k < 16; ++k) xv[k] = xp[k];
        #pragma unroll
        for (int k = 0; k < 10; ++k) {
            int o = t * 20 + 2 * k;
            float al0 = dot16((const float4*)(Ws + o * D_IN), xv);
            float al1 = dot16((const float4*)(Ws + (o + 1) * D_IN), xv);
            float ar0 = dot16((const float4*)(Ws + (40 + o) * D_IN), xv);
            float ar1 = dot16((const float4*)(Ws + (41 + o) * D_IN), xv);
            xl_s[m * (D_H / 2) + (o >> 1)] =
                (u32)f32_to_bf16_rne(al0) | ((u32)f32_to_bf16_rne(al1) << 16);
            xr_s[m * D_H + o]     = ar0 + b1s[o];
            xr_s[m * D_H + o + 1] = ar1 + b1s[o + 1];
        }
    }
    __syncthreads();
    int nb = min(128, n - blockIdx.x * 128);     // nodes in this block
    // xl: nb*20 u32 = nb*5 uint4 (always divisible)
    const uint4* sl = (const uint4*)xl_s;
    uint4* gl = (uint4*)(xl + (size_t)blockIdx.x * 128 * (D_H / 2));
    for (int i = tx; i < nb * 5; i += 256) gl[i] = sl[i];
    // xr: nb*40 f32 = nb*10 float4
    const float4* sr = (const float4*)xr_s;
    float4* gr = (float4*)(xr + (size_t)blockIdx.x * 128 * D_H);
    for (int i = tx; i < nb * 10; i += 256) gr[i] = sr[i];
}

// ---------------- Layer 1: h = relu(mean_gather(xl) + xr), in-place on xr ----
__global__ void gather_node1(const u32* __restrict__ xlp,
                             const int* __restrict__ off,
                             const int* __restrict__ csr,
                             float* __restrict__ hbuf,  // xr in, h out (n x 40)
                             int n) {
    __shared__ __align__(16) float part[4][12][D_H];
    int local = threadIdx.x >> 6;
    int lane  = threadIdx.x & 63;
    int node  = blockIdx.x * 4 + local;
    int g = lane / 5;
    int t = lane - g * 5;
    int deg = 0;
    const uint4* rows = (const uint4*)xlp;   // 5 uint4 per row
    if (node < n) {
        int o0 = off[node], o1 = off[node + 1];
        deg = o1 - o0;
        float a0[8] = {0,0,0,0,0,0,0,0};
        float a1[8] = {0,0,0,0,0,0,0,0};
        float a2[8] = {0,0,0,0,0,0,0,0};
        float a3[8] = {0,0,0,0,0,0,0,0};
        for (int base = o0; base < o1; base += 64) {
            int cnt = min(64, o1 - base);
            int idx = (base + lane < o1) ? csr[base + lane] : 0;
            if (g < 12) {
                for (int j = 0; j < cnt; j += 48) {
                    int j0 = j + g, j1 = j + 12 + g, j2 = j + 24 + g, j3 = j + 36 + g;
                    int s0 = __shfl(idx, j0 & 63);
                    int s1 = __shfl(idx, j1 & 63);
                    int s2 = __shfl(idx, j2 & 63);
                    int s3 = __shfl(idx, j3 & 63);
                    // Clamp out-of-range slots onto s0's row (dup loads coalesce
                    // in L1/MSHR -> no extra L2/L3 traffic, MLP preserved).
                    if (j1 >= cnt) s1 = s0;
                    if (j2 >= cnt) s2 = s0;
                    if (j3 >= cnt) s3 = s0;
                    uint4 w0 = rows[(size_t)s0 * 5 + t];
                    uint4 w1 = rows[(size_t)s1 * 5 + t];
                    uint4 w2 = rows[(size_t)s2 * 5 + t];
                    uint4 w3 = rows[(size_t)s3 * 5 + t];
                    if (j0 < cnt) accum8(a0, w0);
                    if (j1 < cnt) accum8(a1, w1);
                    if (j2 < cnt) accum8(a2, w2);
                    if (j3 < cnt) accum8(a3, w3);
                }
            }
        }
        if (g < 12) {
            #pragma unroll
            for (int k = 0; k < 8; ++k) a0[k] += a1[k] + a2[k] + a3[k];
            float* p = &part[local][g][t * 8];
            ((float4*)p)[0] = make_float4(a0[0], a0[1], a0[2], a0[3]);
            ((float4*)p)[1] = make_float4(a0[4], a0[5], a0[6], a0[7]);
        }
    }
    __syncthreads();
    if (node < n && lane < D_H) {
        float inv = 1.0f / fmaxf((float)deg, 1.0f);
        float agg = 0.0f;
        #pragma unroll
        for (int gg = 0; gg < 12; ++gg) agg += part[local][gg][lane];
        size_t p = (size_t)node * D_H + lane;
        hbuf[p] = fmaxf(agg * inv + hbuf[p], 0.0f);
    }
}

// ---------------- pre2: h2 = bf16(h@W2l^T) compact; hr = h@W2r^T + b2 --------
// Same W-in-LDS fix as pre1 (W2l|W2r = 7.7KB).
__global__ __launch_bounds__(256)
void pre2(float* __restrict__ hbuf, const float* __restrict__ W2l,
          const float* __restrict__ W2r, const float* __restrict__ b2,
          u32* __restrict__ h2, int n) {
    __shared__ __align__(16) float W2s[48 * D_H];            // 7.7 KB: rows 0..23=W2l, 24..47=W2r
    __shared__ float b2s[D_OUT];
    __shared__ __align__(16) u32   h2_s[128 * (D_OUT / 2)];  // 6 KB
    __shared__ __align__(16) float hr_s[128 * D_OUT];        // 12 KB
    int tx = threadIdx.x;
    {
        float4* wd = (float4*)W2s;
        for (int i = tx; i < 48 * 10; i += 256) {
            int r = i / 10, c = i - r * 10;
            float4 v = (r < 24) ? ((const float4*)(W2l + r * D_H))[c]
                                : ((const float4*)(W2r + (r - 24) * D_H))[c];
            wd[i] = v;
        }
        if (tx < D_OUT) b2s[tx] = b2[tx];
    }
    __syncthreads();
    int m  = tx >> 1;
    int t  = tx & 1;
    int node = blockIdx.x * 128 + m;
    if (node < n) {
        float4 hv[10];
        const float4* hp = (const float4*)(hbuf + (size_t)node * D_H);
        #pragma unroll
        for (int k = 0; k < 10; ++k) hv[k] = hp[k];
        #pragma unroll
        for (int k = 0; k < 6; ++k) {
            int o = t * 12 + 2 * k;
            float al0 = dot10((const float4*)(W2s + o * D_H), hv);
            float al1 = dot10((const float4*)(W2s + (o + 1) * D_H), hv);
            float ar0 = dot10((const float4*)(W2s + (24 + o) * D_H), hv);
            float ar1 = dot10((const float4*)(W2s + (25 + o) * D_H), hv);
            h2_s[m * (D_OUT / 2) + (o >> 1)] =
                (u32)f32_to_bf16_rne(al0) | ((u32)f32_to_bf16_rne(al1) << 16);
            hr_s[m * D_OUT + o]     = ar0 + b2s[o];
            hr_s[m * D_OUT + o + 1] = ar1 + b2s[o + 1];
        }
    }
    __syncthreads();
    int nb = min(128, n - blockIdx.x * 128);
    // h2: nb*12 u32 = nb*3 uint4
    const uint4* sl = (const uint4*)h2_s;
    uint4* gl = (uint4*)(h2 + (size_t)blockIdx.x * 128 * (D_OUT / 2));
    for (int i = tx; i < nb * 3; i += 256) gl[i] = sl[i];
    // hr: rows of 24 f32 (6 float4) into stride-40 rows (16B-aligned bursts).
    const float4* sr = (const float4*)hr_s;
    float* grow = hbuf + (size_t)blockIdx.x * 128 * D_H;
    for (int i = tx; i < nb * 6; i += 256) {
        int nl = i / 6, c4 = i - nl * 6;
        *(float4*)(grow + (size_t)nl * D_H + c4 * 4) = sr[i];
    }
}

// ---------------- Layer 2: out = log_softmax(mean_gather(h2) + hr) -----------
__global__ void gather_node2(const u32* __restrict__ h2p,
                             const int* __restrict__ off,
                             const int* __restrict__ csr,
                             const float* __restrict__ hbuf,  // hr rows (stride 40)
                             float* __restrict__ out, int n) {
    __shared__ __align__(16) float part[4][21][D_OUT];
    int local = threadIdx.x >> 6;
    int lane  = threadIdx.x & 63;
    int node  = blockIdx.x * 4 + local;
    int g = lane / 3;
    int t = lane - g * 3;
    int deg = 0;
    const uint4* rows = (const uint4*)h2p;   // 3 uint4 per row
    if (node < n) {
        int o0 = off[node], o1 = off[node + 1];
        deg = o1 - o0;
        float a0[8] = {0,0,0,0,0,0,0,0};
        float a1[8] = {0,0,0,0,0,0,0,0};
        for (int base = o0; base < o1; base += 64) {
            int cnt = min(64, o1 - base);
            int idx = (base + lane < o1) ? csr[base + lane] : 0;
            if (g < 21) {
                for (int j = 0; j < cnt; j += 42) {
                    int j0 = j + g, j1 = j + 21 + g;
                    int s0 = __shfl(idx, j0 & 63);
                    int s1 = __shfl(idx, j1 & 63);
                    // Same clamp trick as gather_node1: dup load hits s0's line.
                    if (j1 >= cnt) s1 = s0;
                    uint4 w0 = rows[(size_t)s0 * 3 + t];
                    uint4 w1 = rows[(size_t)s1 * 3 + t];
                    if (j0 < cnt) accum8(a0, w0);
                    if (j1 < cnt) accum8(a1, w1);
                }
            }
        }
        if (g < 21) {
            #pragma unroll
            for (int k = 0; k < 8; ++k) a0[k] += a1[k];
            float* p = &part[local][g][t * 8];
            ((float4*)p)[0] = make_float4(a0[0], a0[1], a0[2], a0[3]);
            ((float4*)p)[1] = make_float4(a0[4], a0[5], a0[6], a0[7]);
        }
    }
    __syncthreads();
    // Wave-parallel log_softmax: lane k (k<24) holds its own logit in a register;
    // 32-wide butterfly for max and sum (lanes 24..31 seeded -INF / 0).
    float val = 0.0f;
    if (node < n && lane < D_OUT) {
        float inv = 1.0f / fmaxf((float)deg, 1.0f);
        float agg = 0.0f;
        #pragma unroll
        for (int gg = 0; gg < 21; ++gg) agg += part[local][gg][lane];
        val = agg * inv + hbuf[(size_t)node * D_H + lane];
    }
    float m = (lane < D_OUT) ? val : -INFINITY;
    #pragma unroll
    for (int d = 16; d >= 1; d >>= 1) m = fmaxf(m, __shfl_xor(m, d, 32));
    float e = (lane < D_OUT) ? expf(val - m) : 0.0f;
    float se = e;
    #pragma unroll
    for (int d = 16; d >= 1; d >>= 1) se += __shfl_xor(se, d, 32);
    if (node < n && lane < D_OUT)
        out[(size_t)node * D_OUT + lane] = val - m - logf(se);
}

extern "C" void kernel_launch(void* const* d_in, const int* in_sizes, int n_in,
                              void* d_out, int out_size, void* d_ws, size_t ws_size,
                              hipStream_t stream) {
    const float* x   = (const float*)d_in[0];
    const int*   ei  = (const int*)d_in[1];
    const float* W1l = (const float*)d_in[2];
    const float* b1  = (const float*)d_in[3];
    const float* W1r = (const float*)d_in[4];
    const float* W2l = (const float*)d_in[5];
    const float* b2  = (const float*)d_in[6];
    const float* W2r = (const float*)d_in[7];
    float* out = (float*)d_out;

    const int n = in_sizes[0] / D_IN;      // 100000
    const int E = in_sizes[1] / 2;         // 3200000
    const int* src = ei;
    const int* dst = ei + E;

    const int B   = (n + S_NODES - 1) >> S_BITS;   // 391 buckets
    const int NB1 = (E + CH - 1) / CH;             // 391 edge blocks

    // Workspace (~38 MB):
    //  region0: n*40 f32 = 16 MB — bucketed (E u32, 12.8MB) then xr/h/hr (buf0)
    //  xl : n*40 bf16 = 8 MB — xl then h2 (compact n*24 bf16)
    //  off: (n+1) i32
    //  G  : NB1*B i32 ≈ 0.61 MB
    //  bktTotal: B i32 ; bktStart: (B+1) i32
    //  csr: E i32 = 12.8 MB
    char* ws = (char*)d_ws;
    float* buf0     = (float*)ws;
    u32*   bucketed = (u32*)ws;      ws += (size_t)n * D_H * 4;
    u16*   xl       = (u16*)ws;
    u16*   h2       = (u16*)ws;      ws += (size_t)n * D_H * 2;
    int*   off      = (int*)ws;      ws += (((size_t)(n + 1) * 4 + 15) & ~15ull);
    int*   G        = (int*)ws;      ws += (((size_t)NB1 * B * 4 + 15) & ~15ull);
    int*   bktTotal = (int*)ws;      ws += (((size_t)B * 4 + 15) & ~15ull);
    int*   bktStart = (int*)ws;      ws += (((size_t)(B + 1) * 4 + 15) & ~15ull);
    int*   csr      = (int*)ws;

    passA<<<NB1, 256, 0, stream>>>(dst, G, E, B);
    colscan<<<B, 64, 0, stream>>>(G, bktTotal, NB1, B);
    bucketscan<<<1, 64, 0, stream>>>(bktTotal, bktStart, off, B, E, n);
    passB<<<NB1, 256, 0, stream>>>(src, dst, G, bktStart, bucketed, E, B);
    bucket_csr<<<B, 256, 0, stream>>>(bucketed, bktStart, off, csr, n);

    pre1<<<(n + 127) / 128, 256, 0, stream>>>(x, W1l, W1r, b1, (u32*)xl, buf0, n);
    gather_node1<<<(n + 3) / 4, 256, 0, stream>>>((const u32*)xl, off, csr, buf0, n);
    pre2<<<(n + 127) / 128, 256, 0, stream>>>(buf0, W2l, W2r, b2, (u32*)h2, n);
    gather_node2<<<(n + 3) / 4, 256, 0, stream>>>((const u32*)h2, off, csr, buf0, out, n);
}

// Round 10
// 311.341 us; speedup vs baseline: 1.8467x; 1.0003x over previous
//
#include <hip/hip_runtime.h>
#include <math.h>

#define D_IN 64
#define D_H 40
#define D_OUT 24
#define S_BITS 8
#define S_NODES 256      // nodes per bucket
#define CH 8192          // edges per passA/passB block
#define BMAX 512         // max buckets (n <= 131072)

typedef unsigned int u32;
typedef unsigned short u16;

// ---------------- CSR build: atomic-free LDS multisplit ----------------
// passA: per-block histogram of dst buckets (bucket = dst >> 8).
// int4-vectorized edge reads: 4 edges/thread/iter, 1KB/wave-instr.
__global__ void passA(const int* __restrict__ dst, int* __restrict__ G,
                      int E, int B) {
    __shared__ int hist[BMAX];
    int tx = threadIdx.x;
    for (int i = tx; i < B; i += 256) hist[i] = 0;
    __syncthreads();
    int e0 = blockIdx.x * CH;
    int e1 = min(e0 + CH, E);
    for (int e = e0 + tx * 4; e < e1; e += 1024) {
        if (e + 4 <= e1) {
            int4 d4 = *(const int4*)(dst + e);
            atomicAdd(&hist[d4.x >> S_BITS], 1);
            atomicAdd(&hist[d4.y >> S_BITS], 1);
            atomicAdd(&hist[d4.z >> S_BITS], 1);
            atomicAdd(&hist[d4.w >> S_BITS], 1);
        } else {
            for (int q = e; q < e1; ++q)
                atomicAdd(&hist[dst[q] >> S_BITS], 1);
        }
    }
    __syncthreads();
    for (int i = tx; i < B; i += 256) G[(size_t)blockIdx.x * B + i] = hist[i];
}

// colscan: for bucket b, exclusive-scan G[i][b] over blocks i; total -> bktTotal.
__global__ void colscan(int* __restrict__ G, int* __restrict__ bktTotal,
                        int NB1, int B) {
    int b = blockIdx.x;
    int lane = threadIdx.x;      // 64 threads
    int carry = 0;
    for (int base = 0; base < NB1; base += 64) {
        int i = base + lane;
        int orig = (i < NB1) ? G[(size_t)i * B + b] : 0;
        int v = orig;
        #pragma unroll
        for (int d = 1; d < 64; d <<= 1) {
            int t = __shfl_up(v, d);
            if (lane >= d) v += t;
        }
        if (i < NB1) G[(size_t)i * B + b] = carry + v - orig;   // exclusive
        carry += __shfl(v, 63);
    }
    if (lane == 0) bktTotal[b] = carry;
}

// bucketscan: exclusive scan of bucket totals -> bktStart[0..B]; off[n] = E.
__global__ void bucketscan(const int* __restrict__ bktTotal,
                           int* __restrict__ bktStart, int* __restrict__ off,
                           int B, int E, int n) {
    int lane = threadIdx.x;
    int carry = 0;
    for (int base = 0; base < B; base += 64) {
        int i = base + lane;
        int orig = (i < B) ? bktTotal[i] : 0;
        int v = orig;
        #pragma unroll
        for (int d = 1; d < 64; d <<= 1) {
            int t = __shfl_up(v, d);
            if (lane >= d) v += t;
        }
        if (i < B) bktStart[i] = carry + v - orig;
        carry += __shfl(v, 63);
    }
    if (lane == 0) { bktStart[B] = carry; off[n] = E; }
}

// passB: scatter edges into bucket-major order, packed (dstl<<24 | src).
// int4-vectorized src/dst reads; scatter stores unchanged (bucket content is
// order-insensitive: per-node ranks were already atomic-race-ordered).
__global__ void passB(const int* __restrict__ src, const int* __restrict__ dst,
                      const int* __restrict__ G, const int* __restrict__ bktStart,
                      u32* __restrict__ bucketed, int E, int B) {
    __shared__ int baseS[BMAX];
    __shared__ int cnt[BMAX];
    int tx = threadIdx.x;
    for (int i = tx; i < B; i += 256) {
        baseS[i] = bktStart[i] + G[(size_t)blockIdx.x * B + i];
        cnt[i] = 0;
    }
    __syncthreads();
    int e0 = blockIdx.x * CH;
    int e1 = min(e0 + CH, E);
    for (int e = e0 + tx * 4; e < e1; e += 1024) {
        if (e + 4 <= e1) {
            int4 d4 = *(const int4*)(dst + e);
            int4 s4 = *(const int4*)(src + e);
            int b0 = d4.x >> S_BITS, b1 = d4.y >> S_BITS;
            int b2 = d4.z >> S_BITS, b3 = d4.w >> S_BITS;
            int r0 = atomicAdd(&cnt[b0], 1);
            int r1 = atomicAdd(&cnt[b1], 1);
            int r2 = atomicAdd(&cnt[b2], 1);
            int r3 = atomicAdd(&cnt[b3], 1);
            bucketed[baseS[b0] + r0] = ((u32)(d4.x & (S_NODES - 1)) << 24) | (u32)s4.x;
            bucketed[baseS[b1] + r1] = ((u32)(d4.y & (S_NODES - 1)) << 24) | (u32)s4.y;
            bucketed[baseS[b2] + r2] = ((u32)(d4.z & (S_NODES - 1)) << 24) | (u32)s4.z;
            bucketed[baseS[b3] + r3] = ((u32)(d4.w & (S_NODES - 1)) << 24) | (u32)s4.w;
        } else {
            for (int q = e; q < e1; ++q) {
                int d = dst[q];
                int b = d >> S_BITS;
                int r = atomicAdd(&cnt[b], 1);
                bucketed[baseS[b] + r] = ((u32)(d & (S_NODES - 1)) << 24) | (u32)src[q];
            }
        }
    }
}

// bucket_csr: one block per bucket. Count 256 local nodes, LDS scan -> off,
// then rank+place into final CSR. No global scan, no global atomics.
__global__ void bucket_csr(const u32* __restrict__ bucketed,
                           const int* __restrict__ bktStart,
                           int* __restrict__ off, int* __restrict__ csr,
                           int n) {
    __shared__ int degl[S_NODES];
    __shared__ int offl[S_NODES + 1];
    __shared__ int cntl[S_NODES];
    int b  = blockIdx.x;
    int tx = threadIdx.x;        // 256
    int bs = bktStart[b], be = bktStart[b + 1];
    degl[tx] = 0;
    cntl[tx] = 0;
    __syncthreads();
    for (int e = bs + tx; e < be; e += 256)
        atomicAdd(&degl[bucketed[e] >> 24], 1);      // LDS atomic
    __syncthreads();
    int v = degl[tx];
    offl[tx] = v;
    __syncthreads();
    for (int d = 1; d < 256; d <<= 1) {              // Hillis-Steele inclusive
        int t = (tx >= d) ? offl[tx - d] : 0;
        __syncthreads();
        offl[tx] += t;
        __syncthreads();
    }
    int excl = offl[tx] - v;
    __syncthreads();
    offl[tx] = excl;
    if (tx == 255) offl[256] = excl + v;
    __syncthreads();
    int node = b * S_NODES + tx;
    if (node <= n) off[node] = bs + offl[tx];
    for (int e = bs + tx; e < be; e += 256) {
        u32 w = bucketed[e];
        int dl = w >> 24;
        int r = atomicAdd(&cntl[dl], 1);             // LDS atomic
        csr[bs + offl[dl] + r] = (int)(w & 0xFFFFFFu);
    }
}

// ---------------- bf16 helpers ----------------
__device__ inline u16 f32_to_bf16_rne(float f) {
    u32 u = __float_as_uint(f);
    u += 0x7fffu + ((u >> 16) & 1u);
    return (u16)(u >> 16);
}

__device__ inline void accum8(float* a, uint4 w) {
    a[0] += __uint_as_float(w.x << 16);
    a[1] += __uint_as_float(w.x & 0xffff0000u);
    a[2] += __uint_as_float(w.y << 16);
    a[3] += __uint_as_float(w.y & 0xffff0000u);
    a[4] += __uint_as_float(w.z << 16);
    a[5] += __uint_as_float(w.z & 0xffff0000u);
    a[6] += __uint_as_float(w.w << 16);
    a[7] += __uint_as_float(w.w & 0xffff0000u);
}

__device__ inline float dot16(const float4* __restrict__ w, const float4* v) {
    float acc = 0.0f;
    #pragma unroll
    for (int k = 0; k < 16; ++k) {
        float4 a = w[k], b = v[k];
        acc += a.x * b.x + a.y * b.y + a.z * b.z + a.w * b.w;
    }
    return acc;
}

__device__ inline float dot10(const float4* __restrict__ w, const float4* v) {
    float acc = 0.0f;
    #pragma unroll
    for (int k = 0; k < 10; ++k) {
        float4 a = w[k], b = v[k];
        acc += a.x * b.x + a.y * b.y + a.z * b.z + a.w * b.w;
    }
    return acc;
}

// ---------------- pre1: xl = bf16(x@W1l^T), xr = x@W1r^T + b1 ----------------
// W1l|W1r (20.5KB) + b1 staged in LDS (round 5: was latency-bound on global
// W loads at VALUBusy 10.8%). LDS-staged coalesced writeout (round 3).
// __launch_bounds__(256) (round 4: prevents xv[16] scratch spill).
__global__ __launch_bounds__(256)
void pre1(const float* __restrict__ x, const float* __restrict__ W1l,
          const float* __restrict__ W1r, const float* __restrict__ b1,
          u32* __restrict__ xl, float* __restrict__ xr, int n) {
    __shared__ __align__(16) float Ws[80 * D_IN];           // 20.5 KB: rows 0..39=W1l, 40..79=W1r
    __shared__ float b1s[D_H];
    __shared__ __align__(16) u32   xl_s[128 * (D_H / 2)];   // 10 KB
    __shared__ __align__(16) float xr_s[128 * D_H];         // 20 KB
    int tx = threadIdx.x;
    // cooperative W load: 80 rows x 16 float4 = 1280 float4, identity layout
    {
        float4* wd = (float4*)Ws;
        for (int i = tx; i < 80 * 16; i += 256) {
            int r = i >> 4, c = i & 15;
            float4 v = (r < 40) ? ((const float4*)(W1l + r * D_IN))[c]
                                : ((const float4*)(W1r + (r - 40) * D_IN))[c];
            wd[i] = v;
        }
        if (tx < D_H) b1s[tx] = b1[tx];
    }
    __syncthreads();
    int m  = tx >> 1;            // local node 0..127
    int t  = tx & 1;             // half selector
    int node = blockIdx.x * 128 + m;
    if (node < n) {
        float4 xv[16];
        const float4* xp = (const float4*)(x + (size_t)node * D_IN);
        #pragma unroll
        for (int k = 0; k < 16; ++k) xv[k] = xp[k];
        #pragma unroll
        for (int k = 0; k < 10; ++k) {
            int o = t * 20 + 2 * k;
            float al0 = dot16((const float4*)(Ws + o * D_IN), xv);
            float al1 = dot16((const float4*)(Ws + (o + 1) * D_IN), xv);
            float ar0 = dot16((const float4*)(Ws + (40 + o) * D_IN), xv);
            float ar1 = dot16((const float4*)(Ws + (41 + o) * D_IN), xv);
            xl_s[m * (D_H / 2) + (o >> 1)] =
                (u32)f32_to_bf16_rne(al0) | ((u32)f32_to_bf16_rne(al1) << 16);
            xr_s[m * D_H + o]     = ar0 + b1s[o];
            xr_s[m * D_H + o + 1] = ar1 + b1s[o + 1];
        }
    }
    __syncthreads();
    int nb = min(128, n - blockIdx.x * 128);     // nodes in this block
    // xl: nb*20 u32 = nb*5 uint4 (always divisible)
    const uint4* sl = (const uint4*)xl_s;
    uint4* gl = (uint4*)(xl + (size_t)blockIdx.x * 128 * (D_H / 2));
    for (int i = tx; i < nb * 5; i += 256) gl[i] = sl[i];
    // xr: nb*40 f32 = nb*10 float4
    const float4* sr = (const float4*)xr_s;
    float4* gr = (float4*)(xr + (size_t)blockIdx.x * 128 * D_H);
    for (int i = tx; i < nb * 10; i += 256) gr[i] = sr[i];
}

// ---------------- Layer 1: h = relu(mean_gather(xl) + xr), in-place on xr ----
// Round 9: VALUBusy 50% / hbm 44% / MfmaUtil 0 -> mixed VALU+latency bound.
// ~20 of ~80 VALU ops per lane-iter were 64-bit row-address chains. All
// offsets fit 24-bit multiplies (s<100K, row=80B, max 8MB): __umul24 + u32
// byte offset off a uniform base -> single v_mad_u32_u24 + saddr-form load.
__global__ void gather_node1(const u32* __restrict__ xlp,
                             const int* __restrict__ off,
                             const int* __restrict__ csr,
                             float* __restrict__ hbuf,  // xr in, h out (n x 40)
                             int n) {
    __shared__ __align__(16) float part[4][12][D_H];
    int local = threadIdx.x >> 6;
    int lane  = threadIdx.x & 63;
    int node  = blockIdx.x * 4 + local;
    int g = lane / 5;
    int t = lane - g * 5;
    u32 tb = (u32)(t * 16);                  // byte offset of this lane's uint4
    int deg = 0;
    const char* rowb = (const char*)xlp;     // 80 B per row
    if (node < n) {
        int o0 = off[node], o1 = off[node + 1];
        deg = o1 - o0;
        float a0[8] = {0,0,0,0,0,0,0,0};
        float a1[8] = {0,0,0,0,0,0,0,0};
        float a2[8] = {0,0,0,0,0,0,0,0};
        float a3[8] = {0,0,0,0,0,0,0,0};
        for (int base = o0; base < o1; base += 64) {
            int cnt = min(64, o1 - base);
            int idx = (base + lane < o1) ? csr[base + lane] : 0;
            if (g < 12) {
                for (int j = 0; j < cnt; j += 48) {
                    int j0 = j + g, j1 = j + 12 + g, j2 = j + 24 + g, j3 = j + 36 + g;
                    int s0 = __shfl(idx, j0 & 63);
                    int s1 = __shfl(idx, j1 & 63);
                    int s2 = __shfl(idx, j2 & 63);
                    int s3 = __shfl(idx, j3 & 63);
                    // Clamp out-of-range slots onto s0's row (dup loads coalesce
                    // in L1/MSHR -> no extra L2/L3 traffic, MLP preserved).
                    if (j1 >= cnt) s1 = s0;
                    if (j2 >= cnt) s2 = s0;
                    if (j3 >= cnt) s3 = s0;
                    u32 f0 = __umul24((u32)s0, 80u) + tb;
                    u32 f1 = __umul24((u32)s1, 80u) + tb;
                    u32 f2 = __umul24((u32)s2, 80u) + tb;
                    u32 f3 = __umul24((u32)s3, 80u) + tb;
                    uint4 w0 = *(const uint4*)(rowb + f0);
                    uint4 w1 = *(const uint4*)(rowb + f1);
                    uint4 w2 = *(const uint4*)(rowb + f2);
                    uint4 w3 = *(const uint4*)(rowb + f3);
                    if (j0 < cnt) accum8(a0, w0);
                    if (j1 < cnt) accum8(a1, w1);
                    if (j2 < cnt) accum8(a2, w2);
                    if (j3 < cnt) accum8(a3, w3);
                }
            }
        }
        if (g < 12) {
            #pragma unroll
            for (int k = 0; k < 8; ++k) a0[k] += a1[k] + a2[k] + a3[k];
            float* p = &part[local][g][t * 8];
            ((float4*)p)[0] = make_float4(a0[0], a0[1], a0[2], a0[3]);
            ((float4*)p)[1] = make_float4(a0[4], a0[5], a0[6], a0[7]);
        }
    }
    __syncthreads();
    if (node < n && lane < D_H) {
        float inv = 1.0f / fmaxf((float)deg, 1.0f);
        float agg = 0.0f;
        #pragma unroll
        for (int gg = 0; gg < 12; ++gg) agg += part[local][gg][lane];
        u32 p = __umul24((u32)node, (u32)D_H) + (u32)lane;
        hbuf[p] = fmaxf(agg * inv + hbuf[p], 0.0f);
    }
}

// ---------------- pre2: h2 = bf16(h@W2l^T) compact; hr = h@W2r^T + b2 --------
// Same W-in-LDS fix as pre1 (W2l|W2r = 7.7KB).
__global__ __launch_bounds__(256)
void pre2(float* __restrict__ hbuf, const float* __restrict__ W2l,
          const float* __restrict__ W2r, const float* __restrict__ b2,
          u32* __restrict__ h2, int n) {
    __shared__ __align__(16) float W2s[48 * D_H];            // 7.7 KB: rows 0..23=W2l, 24..47=W2r
    __shared__ float b2s[D_OUT];
    __shared__ __align__(16) u32   h2_s[128 * (D_OUT / 2)];  // 6 KB
    __shared__ __align__(16) float hr_s[128 * D_OUT];        // 12 KB
    int tx = threadIdx.x;
    {
        float4* wd = (float4*)W2s;
        for (int i = tx; i < 48 * 10; i += 256) {
            int r = i / 10, c = i - r * 10;
            float4 v = (r < 24) ? ((const float4*)(W2l + r * D_H))[c]
                                : ((const float4*)(W2r + (r - 24) * D_H))[c];
            wd[i] = v;
        }
        if (tx < D_OUT) b2s[tx] = b2[tx];
    }
    __syncthreads();
    int m  = tx >> 1;
    int t  = tx & 1;
    int node = blockIdx.x * 128 + m;
    if (node < n) {
        float4 hv[10];
        const float4* hp = (const float4*)(hbuf + (size_t)node * D_H);
        #pragma unroll
        for (int k = 0; k < 10; ++k) hv[k] = hp[k];
        #pragma unroll
        for (int k = 0; k < 6; ++k) {
            int o = t * 12 + 2 * k;
            float al0 = dot10((const float4*)(W2s + o * D_H), hv);
            float al1 = dot10((const float4*)(W2s + (o + 1) * D_H), hv);
            float ar0 = dot10((const float4*)(W2s + (24 + o) * D_H), hv);
            float ar1 = dot10((const float4*)(W2s + (25 + o) * D_H), hv);
            h2_s[m * (D_OUT / 2) + (o >> 1)] =
                (u32)f32_to_bf16_rne(al0) | ((u32)f32_to_bf16_rne(al1) << 16);
            hr_s[m * D_OUT + o]     = ar0 + b2s[o];
            hr_s[m * D_OUT + o + 1] = ar1 + b2s[o + 1];
        }
    }
    __syncthreads();
    int nb = min(128, n - blockIdx.x * 128);
    // h2: nb*12 u32 = nb*3 uint4
    const uint4* sl = (const uint4*)h2_s;
    uint4* gl = (uint4*)(h2 + (size_t)blockIdx.x * 128 * (D_OUT / 2));
    for (int i = tx; i < nb * 3; i += 256) gl[i] = sl[i];
    // hr: rows of 24 f32 (6 float4) into stride-40 rows (16B-aligned bursts).
    const float4* sr = (const float4*)hr_s;
    float* grow = hbuf + (size_t)blockIdx.x * 128 * D_H;
    for (int i = tx; i < nb * 6; i += 256) {
        int nl = i / 6, c4 = i - nl * 6;
        *(float4*)(grow + (size_t)nl * D_H + c4 * 4) = sr[i];
    }
}

// ---------------- Layer 2: out = log_softmax(mean_gather(h2) + hr) -----------
// Same u24 32-bit addressing as gather_node1 (rows 48 B).
__global__ void gather_node2(const u32* __restrict__ h2p,
                             const int* __restrict__ off,
                             const int* __restrict__ csr,
                             const float* __restrict__ hbuf,  // hr rows (stride 40)
                             float* __restrict__ out, int n) {
    __shared__ __align__(16) float part[4][21][D_OUT];
    int local = threadIdx.x >> 6;
    int lane  = threadIdx.x & 63;
    int node  = blockIdx.x * 4 + local;
    int g = lane / 3;
    int t = lane - g * 3;
    u32 tb = (u32)(t * 16);
    int deg = 0;
    const char* rowb = (const char*)h2p;     // 48 B per row
    if (node < n) {
        int o0 = off[node], o1 = off[node + 1];
        deg = o1 - o0;
        float a0[8] = {0,0,0,0,0,0,0,0};
        float a1[8] = {0,0,0,0,0,0,0,0};
        for (int base = o0; base < o1; base += 64) {
            int cnt = min(64, o1 - base);
            int idx = (base + lane < o1) ? csr[base + lane] : 0;
            if (g < 21) {
                for (int j = 0; j < cnt; j += 42) {
                    int j0 = j + g, j1 = j + 21 + g;
                    int s0 = __shfl(idx, j0 & 63);
                    int s1 = __shfl(idx, j1 & 63);
                    // Same clamp trick as gather_node1: dup load hits s0's line.
                    if (j1 >= cnt) s1 = s0;
                    u32 f0 = __umul24((u32)s0, 48u) + tb;
                    u32 f1 = __umul24((u32)s1, 48u) + tb;
                    uint4 w0 = *(const uint4*)(rowb + f0);
                    uint4 w1 = *(const uint4*)(rowb + f1);
                    if (j0 < cnt) accum8(a0, w0);
                    if (j1 < cnt) accum8(a1, w1);
                }
            }
        }
        if (g < 21) {
            #pragma unroll
            for (int k = 0; k < 8; ++k) a0[k] += a1[k];
            float* p = &part[local][g][t * 8];
            ((float4*)p)[0] = make_float4(a0[0], a0[1], a0[2], a0[3]);
            ((float4*)p)[1] = make_float4(a0[4], a0[5], a0[6], a0[7]);
        }
    }
    __syncthreads();
    // Wave-parallel log_softmax: lane k (k<24) holds its own logit in a register;
    // 32-wide butterfly for max and sum (lanes 24..31 seeded -INF / 0).
    float val = 0.0f;
    if (node < n && lane < D_OUT) {
        float inv = 1.0f / fmaxf((float)deg, 1.0f);
        float agg = 0.0f;
        #pragma unroll
        for (int gg = 0; gg < 21; ++gg) agg += part[local][gg][lane];
        val = agg * inv + hbuf[__umul24((u32)node, (u32)D_H) + (u32)lane];
    }
    float m = (lane < D_OUT) ? val : -INFINITY;
    #pragma unroll
    for (int d = 16; d >= 1; d >>= 1) m = fmaxf(m, __shfl_xor(m, d, 32));
    float e = (lane < D_OUT) ? expf(val - m) : 0.0f;
    float se = e;
    #pragma unroll
    for (int d = 16; d >= 1; d >>= 1) se += __shfl_xor(se, d, 32);
    if (node < n && lane < D_OUT)
        out[__umul24((u32)node, (u32)D_OUT) + (u32)lane] = val - m - logf(se);
}

extern "C" void kernel_launch(void* const* d_in, const int* in_sizes, int n_in,
                              void* d_out, int out_size, void* d_ws, size_t ws_size,
                              hipStream_t stream) {
    const float* x   = (const float*)d_in[0];
    const int*   ei  = (const int*)d_in[1];
    const float* W1l = (const float*)d_in[2];
    const float* b1  = (const float*)d_in[3];
    const float* W1r = (const float*)d_in[4];
    const float* W2l = (const float*)d_in[5];
    const float* b2  = (const float*)d_in[6];
    const float* W2r = (const float*)d_in[7];
    float* out = (float*)d_out;

    const int n = in_sizes[0] / D_IN;      // 100000
    const int E = in_sizes[1] / 2;         // 3200000
    const int* src = ei;
    const int* dst = ei + E;

    const int B   = (n + S_NODES - 1) >> S_BITS;   // 391 buckets
    const int NB1 = (E + CH - 1) / CH;             // 391 edge blocks

    // Workspace (~38 MB):
    //  region0: n*40 f32 = 16 MB — bucketed (E u32, 12.8MB) then xr/h/hr (buf0)
    //  xl : n*40 bf16 = 8 MB — xl then h2 (compact n*24 bf16)
    //  off: (n+1) i32
    //  G  : NB1*B i32 ≈ 0.61 MB
    //  bktTotal: B i32 ; bktStart: (B+1) i32
    //  csr: E i32 = 12.8 MB
    char* ws = (char*)d_ws;
    float* buf0     = (float*)ws;
    u32*   bucketed = (u32*)ws;      ws += (size_t)n * D_H * 4;
    u16*   xl       = (u16*)ws;
    u16*   h2       = (u16*)ws;      ws += (size_t)n * D_H * 2;
    int*   off      = (int*)ws;      ws += (((size_t)(n + 1) * 4 + 15) & ~15ull);
    int*   G        = (int*)ws;      ws += (((size_t)NB1 * B * 4 + 15) & ~15ull);
    int*   bktTotal = (int*)ws;      ws += (((size_t)B * 4 + 15) & ~15ull);
    int*   bktStart = (int*)ws;      ws += (((size_t)(B + 1) * 4 + 15) & ~15ull);
    int*   csr      = (int*)ws;

    passA<<<NB1, 256, 0, stream>>>(dst, G, E, B);
    colscan<<<B, 64, 0, stream>>>(G, bktTotal, NB1, B);
    bucketscan<<<1, 64, 0, stream>>>(bktTotal, bktStart, off, B, E, n);
    passB<<<NB1, 256, 0, stream>>>(src, dst, G, bktStart, bucketed, E, B);
    bucket_csr<<<B, 256, 0, stream>>>(bucketed, bktStart, off, csr, n);

    pre1<<<(n + 127) / 128, 256, 0, stream>>>(x, W1l, W1r, b1, (u32*)xl, buf0, n);
    gather_node1<<<(n + 3) / 4, 256, 0, stream>>>((const u32*)xl, off, csr, buf0, n);
    pre2<<<(n + 127) / 128, 256, 0, stream>>>(buf0, W2l, W2r, b2, (u32*)h2, n);
    gather_node2<<<(n + 3) / 4, 256, 0, stream>>>((const u32*)h2, off, csr, buf0, out, n);
}